// Round 9
// baseline (1185.724 us; speedup 1.0000x reference)
//
#include <hip/hip_runtime.h>
#include <hip/hip_bf16.h>

#define BB 256
#define SS 32
#define II 128
#define HH 256
#define LBL 200
#define NSUBS 491
#define NATOMS_N 8000
#define NMOL_N 600

typedef const float* fp;

__device__ __forceinline__ float sigm(float x) { return 1.f / (1.f + expf(-x)); }

// ---------------------------------------------------------------------------
// prep (102 blocks): idxv, mstart, masked w_masklin, and register-layout GRU
// weights wR[row][j], row = ((g*4+q)*3+G)*64 + kk  -> value whh_g[G*256+j][q*64+kk]
// so gru thread (j,q) loads its 192 weights at stride-256, coalesced in j.
// ---------------------------------------------------------------------------
__global__ __launch_bounds__(256) void prep_kernel(
    const int* __restrict__ mask, int* __restrict__ idxv,
    const int* __restrict__ seg, int* __restrict__ mstart,
    fp w_masklin, fp ddi, float* __restrict__ mw,
    fp whh_c, fp whh_p, float* __restrict__ wR)
{
  int bx = blockIdx.x, tid = threadIdx.x;
  if (bx == 0) {                         // idx[b] = clamp(sum(mask[b,:]) - 1)
    int s = 0;
    const int* mrow = mask + tid * SS;
    for (int t = 0; t < SS; ++t) s += mrow[t];
    s -= 1;
    if (s < 0) s = 0;
    if (s > SS - 1) s = SS - 1;
    idxv[tid] = s;
  } else if (bx == 1) {                  // mstart[m] = lower_bound(seg, m)
    for (int m = tid; m <= NMOL_N; m += 256) {
      if (m == NMOL_N) { mstart[m] = NATOMS_N; continue; }
      int lo = 0, hi = NATOMS_N;
      while (lo < hi) {
        int mid = (lo + hi) >> 1;
        if (seg[mid] < m) lo = mid + 1; else hi = mid;
      }
      mstart[m] = lo;
    }
  } else if (bx < 6) {                   // mw[s][l] = w_masklin[s][l]*ddi[l][s]
    for (int o = (bx - 2) * 256 + tid; o < NSUBS * LBL; o += 4 * 256) {
      int s = o / LBL, l = o - s * LBL;
      mw[o] = w_masklin[o] * ddi[l * NSUBS + s];
    }
  } else {                               // weight repack: 96 blocks x 16 rows
    for (int rr = 0; rr < 16; ++rr) {
      int row = (bx - 6) * 16 + rr;      // 0..1535
      int g = row / 768;
      int rem = row - g * 768;
      int q = rem / 192;
      int rem2 = rem - q * 192;
      int G = rem2 >> 6;
      int kk = rem2 & 63;
      fp whh = g ? whh_p : whh_c;
      wR[(size_t)row * 256 + tid] = whh[(size_t)(G * 256 + tid) * HH + q * 64 + kk];
    }
  }
}

// ---------------------------------------------------------------------------
// xp = x @ w_ih.T + b_ih, fp32. xp[g][b*SS+t][768], 8192 rows per g.
// grid (24576, 2): 512 mtiles x 48 ntiles
// ---------------------------------------------------------------------------
__global__ __launch_bounds__(256) void xp_gemm(
    fp x_c, fp x_p, fp wih_c, fp wih_p, fp bih_c, fp bih_p,
    float* __restrict__ xp)
{
  int g = blockIdx.y;
  fp x = g ? x_p : x_c;
  fp wih = g ? wih_p : wih_c;
  fp bih = g ? bih_p : bih_c;
  float* xpo = xp + (size_t)g * 8192 * 768;

  int bx = blockIdx.x;
  int mt = bx / 48, nt = bx - mt * 48;
  int m0 = mt << 4, n0 = nt << 4;
  int tid = threadIdx.x;

  __shared__ float As[16][132];
  __shared__ float Ws[16][132];
  for (int i = tid; i < 2048; i += 256) {
    int r = i >> 7, k = i & 127;
    As[r][k] = x[(size_t)(m0 + r) * II + k];
    Ws[r][k] = wih[(size_t)(n0 + r) * II + k];
  }
  __syncthreads();

  int ni = tid & 15, mi = tid >> 4;
  float acc = 0.f;
#pragma unroll 8
  for (int k = 0; k < II; ++k) acc = fmaf(As[mi][k], Ws[ni][k], acc);
  xpo[(size_t)(m0 + mi) * 768 + n0 + ni] = acc + bih[n0 + ni];
}

// ---------------------------------------------------------------------------
// fully-fused MPNN: one block per molecule (<=14 atoms).
// ---------------------------------------------------------------------------
__global__ __launch_bounds__(256) void mpnn_mol(
    const int* __restrict__ fingerprints, fp embed_fp, fp adj,
    const int* __restrict__ mstart, fp w_g0, fp b_g0, fp w_g1, fp b_g1,
    float* __restrict__ mol)
{
  int m = blockIdx.x, tid = threadIdx.x;
  int a0 = mstart[m], a1 = mstart[m + 1];
  int sz = a1 - a0;
  if (sz < 0) sz = 0;
  if (sz > 14) sz = 14;

  __shared__ float v[14][260];
  __shared__ float adjb[14][16];

#pragma unroll
  for (int i = 0; i < 14; ++i) {
    float val = 0.f;
    if (i < sz) {
      int f = fingerprints[a0 + i] & 1023;
      val = embed_fp[(size_t)f * HH + tid];
    }
    v[i][tid] = val;
  }
  if (tid < 224) {
    int i = tid >> 4, jj = tid & 15;
    float a = 0.f;
    if (i < sz && jj < sz)
      a = adj[(size_t)(a0 + i) * NATOMS_N + a0 + jj];
    adjb[i][jj] = a;
  }
  __syncthreads();

  float acc[14];
  for (int rd = 0; rd < 2; ++rd) {
    const float* wp0 = (rd ? w_g1 : w_g0) + tid;
#pragma unroll
    for (int i = 0; i < 14; ++i) acc[i] = 0.f;
    for (int k = 0; k < HH; k += 4) {
      float w0 = wp0[(size_t)k * HH];
      float w1 = wp0[(size_t)(k + 1) * HH];
      float w2 = wp0[(size_t)(k + 2) * HH];
      float w3 = wp0[(size_t)(k + 3) * HH];
#pragma unroll
      for (int i = 0; i < 14; ++i) {
        float4 vv = *(const float4*)&v[i][k];
        acc[i] = fmaf(vv.x, w0, acc[i]);
        acc[i] = fmaf(vv.y, w1, acc[i]);
        acc[i] = fmaf(vv.z, w2, acc[i]);
        acc[i] = fmaf(vv.w, w3, acc[i]);
      }
    }
    float bias = (rd ? b_g1 : b_g0)[tid];
    float hreg[14];
#pragma unroll
    for (int i = 0; i < 14; ++i) hreg[i] = fmaxf(acc[i] + bias, 0.f);
#pragma unroll
    for (int i = 0; i < 14; ++i) {
      float s = hreg[i];
#pragma unroll
      for (int jj = 0; jj < 14; ++jj) s = fmaf(adjb[i][jj], hreg[jj], s);
      acc[i] = s;
    }
    if (rd == 0) {
      __syncthreads();
#pragma unroll
      for (int i = 0; i < 14; ++i) v[i][tid] = acc[i];
      __syncthreads();
    }
  }
  float msum = 0.f;
#pragma unroll
  for (int i = 0; i < 14; ++i) if (i < sz) msum += acc[i];
  mol[(size_t)m * HH + tid] = msum;
}

// ---------------------------------------------------------------------------
// mpnn_emb^T[h][d] = sum_m avg[d][m] * mol[m][h]
// ---------------------------------------------------------------------------
__global__ __launch_bounds__(256) void mpnn_emb_k(
    fp avg, const float* __restrict__ mol, float* __restrict__ embT)
{
  int d = blockIdx.x, tid = threadIdx.x;
  float acc = 0.f;
  for (int m = 0; m < NMOL_N; ++m)
    acc += avg[d * NMOL_N + m] * mol[(size_t)m * HH + tid];
  embT[(size_t)tid * LBL + d] = acc;
}

// ---------------------------------------------------------------------------
// GRU with register-resident weights: 256 blocks x 1024 threads (1 block/CU,
// forced by LDS pad). Block = (g, batch-pair). Thread (j = tid&255,
// q = tid>>8) holds W[gate r/z/n][j][q*64 .. q*64+63] in 192 VGPRs, loaded
// ONCE. Per step: dots from registers x LDS-broadcast h, 4-way partial
// reduction in LDS, gate math by threads <512, h stays in LDS. Zero weight
// re-streaming (was 6.4 GB of L2 traffic in round 8).
// ---------------------------------------------------------------------------
__global__ __launch_bounds__(1024) void gru_reg(
    fp xp, fp wR, fp bhh_c, fp bhh_p,
    float* __restrict__ hcat, const int* __restrict__ idxv)
{
  int blk = blockIdx.x;
  int g = blk >> 7;
  int pair = blk & 127;
  int b1 = pair * 2, b2 = b1 + 1;
  int tid = threadIdx.x;
  int j = tid & 255;
  int q = tid >> 8;                    // k-quarter 0..3
  int k0 = q << 6;

  __shared__ float h1s[260];
  __shared__ float h2s[260];
  __shared__ float red[24][256];
  __shared__ float pad_force[14848];   // 58 KB: forces 1 block/CU

  // weights -> registers (192 VGPRs), coalesced in j
  const float* wbase = wR + (size_t)(g * 4 + q) * 3 * 64 * 256 + j;
  float wr0[64], wr1[64], wr2[64];
#pragma unroll
  for (int kk = 0; kk < 64; ++kk) wr0[kk] = wbase[(size_t)kk * 256];
#pragma unroll
  for (int kk = 0; kk < 64; ++kk) wr1[kk] = wbase[(size_t)(64 + kk) * 256];
#pragma unroll
  for (int kk = 0; kk < 64; ++kk) wr2[kk] = wbase[(size_t)(128 + kk) * 256];

  if (tid < 256) { h1s[tid] = 0.f; h2s[tid] = 0.f; }

  fp bhh = g ? bhh_p : bhh_c;
  const float* xpg = xp + (size_t)g * 8192 * 768;
  float br = 0.f, bz = 0.f, bn = 0.f;
  int myb = 0, myid = -1;
  if (tid < 512) {
    br = bhh[j]; bz = bhh[j + 256]; bn = bhh[j + 512];
    myb = (q == 0) ? b1 : b2;
    myid = idxv[myb];
  }
  if (idxv[0] < -1) { pad_force[tid] = 0.f; h1s[0] = pad_force[tid]; } // never
  __syncthreads();

  for (int t = 0; t < SS; ++t) {
    // xp prefetch for this step (latency hidden behind the dot loop)
    float xr = 0.f, xz = 0.f, xn = 0.f;
    if (tid < 512) {
      const float* xrow = xpg + ((size_t)myb * SS + t) * 768;
      xr = xrow[j]; xz = xrow[j + 256]; xn = xrow[j + 512];
    }

    float s1r = 0.f, s1z = 0.f, s1n = 0.f;
    float s2r = 0.f, s2z = 0.f, s2n = 0.f;
#pragma unroll
    for (int kk = 0; kk < 64; kk += 4) {
      float4 a1 = *(const float4*)&h1s[k0 + kk];
      float4 a2 = *(const float4*)&h2s[k0 + kk];
      s1r = fmaf(a1.x, wr0[kk], s1r);     s1r = fmaf(a1.y, wr0[kk + 1], s1r);
      s1r = fmaf(a1.z, wr0[kk + 2], s1r); s1r = fmaf(a1.w, wr0[kk + 3], s1r);
      s1z = fmaf(a1.x, wr1[kk], s1z);     s1z = fmaf(a1.y, wr1[kk + 1], s1z);
      s1z = fmaf(a1.z, wr1[kk + 2], s1z); s1z = fmaf(a1.w, wr1[kk + 3], s1z);
      s1n = fmaf(a1.x, wr2[kk], s1n);     s1n = fmaf(a1.y, wr2[kk + 1], s1n);
      s1n = fmaf(a1.z, wr2[kk + 2], s1n); s1n = fmaf(a1.w, wr2[kk + 3], s1n);
      s2r = fmaf(a2.x, wr0[kk], s2r);     s2r = fmaf(a2.y, wr0[kk + 1], s2r);
      s2r = fmaf(a2.z, wr0[kk + 2], s2r); s2r = fmaf(a2.w, wr0[kk + 3], s2r);
      s2z = fmaf(a2.x, wr1[kk], s2z);     s2z = fmaf(a2.y, wr1[kk + 1], s2z);
      s2z = fmaf(a2.z, wr1[kk + 2], s2z); s2z = fmaf(a2.w, wr1[kk + 3], s2z);
      s2n = fmaf(a2.x, wr2[kk], s2n);     s2n = fmaf(a2.y, wr2[kk + 1], s2n);
      s2n = fmaf(a2.z, wr2[kk + 2], s2n); s2n = fmaf(a2.w, wr2[kk + 3], s2n);
    }
    red[q * 6 + 0][j] = s1r; red[q * 6 + 1][j] = s1z; red[q * 6 + 2][j] = s1n;
    red[q * 6 + 3][j] = s2r; red[q * 6 + 4][j] = s2z; red[q * 6 + 5][j] = s2n;
    __syncthreads();

    if (tid < 512) {
      int base = q * 3;                // q=0 -> batch1 rows, q=1 -> batch2 rows
      float sr = red[base + 0][j] + red[base + 6][j] + red[base + 12][j] + red[base + 18][j];
      float sz = red[base + 1][j] + red[base + 7][j] + red[base + 13][j] + red[base + 19][j];
      float sn = red[base + 2][j] + red[base + 8][j] + red[base + 14][j] + red[base + 20][j];
      float* hs = (q == 0) ? h1s : h2s;
      float hold = hs[j];
      float r = sigm(xr + sr + br);
      float z = sigm(xz + sz + bz);
      float n = tanhf(xn + r * (sn + bn));
      float hnew = (1.f - z) * n + z * hold;
      hs[j] = hnew;
      if (t == myid) hcat[(size_t)myb * 512 + g * 256 + j] = fmaxf(hnew, 0.f);
    }
    __syncthreads();
  }
}

// ---------------------------------------------------------------------------
// fp32 GEMM for query: C[M,N] = A[M,K] @ W[K,N] + bias
// ---------------------------------------------------------------------------
__global__ __launch_bounds__(256) void gemm_f32(
    const float* __restrict__ A, fp W, fp bias, float* __restrict__ C,
    int M, int N, int K)
{
  int ntiles = N >> 4;
  int mt = blockIdx.x / ntiles, nt = blockIdx.x - mt * ntiles;
  int m0 = mt << 4, n0 = nt << 4;
  int tid = threadIdx.x;
  int ni = tid & 15, mi = tid >> 4;
  __shared__ float As[16][68];
  float acc = 0.f;
  for (int k0 = 0; k0 < K; k0 += 64) {
    __syncthreads();
    for (int i = tid; i < 1024; i += 256) {
      int r = i >> 6, kk = i & 63;
      As[r][kk] = A[(size_t)(m0 + r) * K + k0 + kk];
    }
    __syncthreads();
    const float* wp = W + (size_t)k0 * N + n0 + ni;
#pragma unroll 4
    for (int kk = 0; kk < 64; ++kk)
      acc = fmaf(As[mi][kk], wp[(size_t)kk * N], acc);
  }
  acc += bias[n0 + ni];
  C[(size_t)(m0 + mi) * N + n0 + ni] = acc;
}

// ---------------------------------------------------------------------------
// fused tail per batch row: match/x2/LN (mpnn_att) + bip/masked-linear + mul
// ---------------------------------------------------------------------------
__global__ __launch_bounds__(256) void tail_fused(
    const float* __restrict__ query, const float* __restrict__ embT,
    fp w_out, fp b_out, fp gamma, fp beta,
    fp w_bip, fp b_bip, const float* __restrict__ mw,
    float* __restrict__ out)
{
  int b = blockIdx.x, tid = threadIdx.x;
  __shared__ float q[HH];
  __shared__ float mrow[LBL];
  __shared__ float bips[NSUBS];
  __shared__ float red[256];
  q[tid] = query[(size_t)b * HH + tid];
  __syncthreads();
  if (tid < LBL) {
    float acc = 0.f;
    for (int k = 0; k < HH; ++k) acc += q[k] * embT[(size_t)k * LBL + tid];
    mrow[tid] = sigm(acc);
  }
  for (int s = tid; s < NSUBS; s += 256) {
    float acc = b_bip[s];
    for (int k = 0; k < HH; ++k) acc += q[k] * w_bip[(size_t)k * NSUBS + s];
    bips[s] = acc;
  }
  __syncthreads();
  float x2 = 0.f;
  if (tid < LBL) {
    float acc = b_out[tid] + mrow[tid];
    for (int jj = 0; jj < LBL; ++jj) acc += mrow[jj] * w_out[jj * LBL + tid];
    x2 = acc;
  }
  red[tid] = (tid < LBL) ? x2 : 0.f;
  __syncthreads();
  for (int s = 128; s > 0; s >>= 1) {
    if (tid < s) red[tid] += red[tid + s];
    __syncthreads();
  }
  float mu = red[0] / (float)LBL;
  __syncthreads();
  float dv = (tid < LBL) ? (x2 - mu) : 0.f;
  red[tid] = dv * dv;
  __syncthreads();
  for (int s = 128; s > 0; s >>= 1) {
    if (tid < s) red[tid] += red[tid + s];
    __syncthreads();
  }
  float var = red[0] / (float)LBL;
  if (tid < LBL) {
    float matt = (x2 - mu) * rsqrtf(var + 1e-5f) * gamma[tid] + beta[tid];
    float acc = 0.f;
    for (int s = 0; s < NSUBS; ++s) acc += bips[s] * mw[(size_t)s * LBL + tid];
    out[(size_t)b * LBL + tid] = acc * matt;
  }
}

// ---------------------------------------------------------------------------
extern "C" void kernel_launch(void* const* d_in, const int* in_sizes, int n_in,
                              void* d_out, int out_size, void* d_ws, size_t ws_size,
                              hipStream_t stream)
{
  fp x_c   = (fp)d_in[0];
  fp x_p   = (fp)d_in[1];
  const int* mask = (const int*)d_in[2];
  fp wih_c = (fp)d_in[3];
  fp whh_c = (fp)d_in[4];
  fp bih_c = (fp)d_in[5];
  fp bhh_c = (fp)d_in[6];
  fp wih_p = (fp)d_in[7];
  fp whh_p = (fp)d_in[8];
  fp bih_p = (fp)d_in[9];
  fp bhh_p = (fp)d_in[10];
  fp w_query = (fp)d_in[11];
  fp b_query = (fp)d_in[12];
  fp w_bip = (fp)d_in[13];
  fp b_bip = (fp)d_in[14];
  fp w_masklin = (fp)d_in[15];
  fp ddi = (fp)d_in[16];
  fp embed_fp = (fp)d_in[17];
  const int* fingerprints = (const int*)d_in[18];
  fp adj = (fp)d_in[19];
  const int* seg = (const int*)d_in[20];
  fp w_g0 = (fp)d_in[21];
  fp b_g0 = (fp)d_in[22];
  fp w_g1 = (fp)d_in[23];
  fp b_g1 = (fp)d_in[24];
  fp avg = (fp)d_in[25];
  fp w_out = (fp)d_in[26];
  fp b_out = (fp)d_in[27];
  fp gamma = (fp)d_in[28];
  fp beta = (fp)d_in[29];
  float* out = (float*)d_out;

  char* w = (char*)d_ws;
  size_t off = 0;
  auto alloc = [&](size_t bytes) -> void* {
    void* p = w + off;
    off = (off + bytes + 255) & ~(size_t)255;
    return p;
  };

  float* xp   = (float*)alloc((size_t)2 * 8192 * 768 * 4);   // 50.3 MB
  float* wR   = (float*)alloc((size_t)1536 * 256 * 4);       // 1.57 MB
  float* mol  = (float*)alloc((size_t)NMOL_N * HH * 4);
  float* embT = (float*)alloc((size_t)HH * LBL * 4);
  float* hcat = (float*)alloc((size_t)BB * 2 * HH * 4);
  float* query = (float*)alloc((size_t)BB * HH * 4);
  float* mw   = (float*)alloc((size_t)NSUBS * LBL * 4);
  int* idxv   = (int*)alloc(256 * 4);
  int* mstart = (int*)alloc((NMOL_N + 1) * 4);

  prep_kernel<<<102, 256, 0, stream>>>(mask, idxv, seg, mstart, w_masklin, ddi,
                                       mw, whh_c, whh_p, wR);

  xp_gemm<<<dim3(24576, 2), 256, 0, stream>>>(x_c, x_p, wih_c, wih_p,
                                              bih_c, bih_p, xp);

  mpnn_mol<<<NMOL_N, 256, 0, stream>>>(fingerprints, embed_fp, adj, mstart,
                                       w_g0, b_g0, w_g1, b_g1, mol);
  mpnn_emb_k<<<LBL, 256, 0, stream>>>(avg, mol, embT);

  gru_reg<<<256, 1024, 0, stream>>>(xp, wR, bhh_c, bhh_p, hcat, idxv);

  gemm_f32<<<256, 256, 0, stream>>>(hcat, w_query, b_query, query, BB, HH, 2 * HH);
  tail_fused<<<BB, 256, 0, stream>>>(query, embT, w_out, b_out, gamma, beta,
                                     w_bip, b_bip, mw, out);
}

// Round 11
// 1047.273 us; speedup vs baseline: 1.1322x; 1.1322x over previous
//
#include <hip/hip_runtime.h>
#include <hip/hip_bf16.h>
#include <hip/hip_fp16.h>

#define BB 256
#define SS 32
#define II 128
#define HH 256
#define LBL 200
#define NSUBS 491
#define NATOMS_N 8000
#define NMOL_N 600

typedef const float* fp;

__device__ __forceinline__ float sigm(float x) { return 1.f / (1.f + expf(-x)); }
__device__ __forceinline__ float hlo(unsigned u) {
  return __half2float(__ushort_as_half((unsigned short)(u & 0xffffu)));
}
__device__ __forceinline__ float hhi(unsigned u) {
  return __half2float(__ushort_as_half((unsigned short)(u >> 16)));
}

// ---------------------------------------------------------------------------
// prep (134 blocks): idxv, mstart, masked w_masklin, and fp16-packed GRU
// weights wPh[(g*64+k4)*768 + gate*256 + j] = uint2 of 4 fp16 weights
// whh_g[gate*256+j][k4*4 .. k4*4+3]. Halves the per-step L2 stream vs fp32;
// fp16 (10-bit mantissa) keeps quantization 8x tighter than bf16 (r10 fail).
// ---------------------------------------------------------------------------
__global__ __launch_bounds__(256) void prep_kernel(
    const int* __restrict__ mask, int* __restrict__ idxv,
    const int* __restrict__ seg, int* __restrict__ mstart,
    fp w_masklin, fp ddi, float* __restrict__ mw,
    fp whh_c, fp whh_p, uint2* __restrict__ wPh)
{
  int bx = blockIdx.x, tid = threadIdx.x;
  if (bx == 0) {                         // idx[b] = clamp(sum(mask[b,:]) - 1)
    int s = 0;
    const int* mrow = mask + tid * SS;
    for (int t = 0; t < SS; ++t) s += mrow[t];
    s -= 1;
    if (s < 0) s = 0;
    if (s > SS - 1) s = SS - 1;
    idxv[tid] = s;
  } else if (bx == 1) {                  // mstart[m] = lower_bound(seg, m)
    for (int m = tid; m <= NMOL_N; m += 256) {
      if (m == NMOL_N) { mstart[m] = NATOMS_N; continue; }
      int lo = 0, hi = NATOMS_N;
      while (lo < hi) {
        int mid = (lo + hi) >> 1;
        if (seg[mid] < m) lo = mid + 1; else hi = mid;
      }
      mstart[m] = lo;
    }
  } else if (bx < 6) {                   // mw[s][l] = w_masklin[s][l]*ddi[l][s]
    for (int o = (bx - 2) * 256 + tid; o < NSUBS * LBL; o += 4 * 256) {
      int s = o / LBL, l = o - s * LBL;
      mw[o] = w_masklin[o] * ddi[l * NSUBS + s];
    }
  } else {                               // weight pack: one (g, k4) per block
    int lin = bx - 6;                    // 0..127
    int g = lin >> 6;
    int k4 = lin & 63;
    fp whh = g ? whh_p : whh_c;
    uint2* dst = wPh + (size_t)(g * 64 + k4) * 768;
#pragma unroll
    for (int gate = 0; gate < 3; ++gate) {
      const float* src = whh + (size_t)(gate * 256 + tid) * HH + k4 * 4;
      unsigned s0 = __half_as_ushort(__float2half(src[0]));
      unsigned s1 = __half_as_ushort(__float2half(src[1]));
      unsigned s2 = __half_as_ushort(__float2half(src[2]));
      unsigned s3 = __half_as_ushort(__float2half(src[3]));
      uint2 u;
      u.x = s0 | (s1 << 16);
      u.y = s2 | (s3 << 16);
      dst[gate * 256 + tid] = u;
    }
  }
}

// ---------------------------------------------------------------------------
// xp = x @ w_ih.T + b_ih, fp32. xp[g][b*SS+t][768], 8192 rows per g.
// grid (24576, 2): 512 mtiles x 48 ntiles
// ---------------------------------------------------------------------------
__global__ __launch_bounds__(256) void xp_gemm(
    fp x_c, fp x_p, fp wih_c, fp wih_p, fp bih_c, fp bih_p,
    float* __restrict__ xp)
{
  int g = blockIdx.y;
  fp x = g ? x_p : x_c;
  fp wih = g ? wih_p : wih_c;
  fp bih = g ? bih_p : bih_c;
  float* xpo = xp + (size_t)g * 8192 * 768;

  int bx = blockIdx.x;
  int mt = bx / 48, nt = bx - mt * 48;
  int m0 = mt << 4, n0 = nt << 4;
  int tid = threadIdx.x;

  __shared__ float As[16][132];
  __shared__ float Ws[16][132];
  for (int i = tid; i < 2048; i += 256) {
    int r = i >> 7, k = i & 127;
    As[r][k] = x[(size_t)(m0 + r) * II + k];
    Ws[r][k] = wih[(size_t)(n0 + r) * II + k];
  }
  __syncthreads();

  int ni = tid & 15, mi = tid >> 4;
  float acc = 0.f;
#pragma unroll 8
  for (int k = 0; k < II; ++k) acc = fmaf(As[mi][k], Ws[ni][k], acc);
  xpo[(size_t)(m0 + mi) * 768 + n0 + ni] = acc + bih[n0 + ni];
}

// ---------------------------------------------------------------------------
// fully-fused MPNN: one block per molecule (<=14 atoms).
// ---------------------------------------------------------------------------
__global__ __launch_bounds__(256) void mpnn_mol(
    const int* __restrict__ fingerprints, fp embed_fp, fp adj,
    const int* __restrict__ mstart, fp w_g0, fp b_g0, fp w_g1, fp b_g1,
    float* __restrict__ mol)
{
  int m = blockIdx.x, tid = threadIdx.x;
  int a0 = mstart[m], a1 = mstart[m + 1];
  int sz = a1 - a0;
  if (sz < 0) sz = 0;
  if (sz > 14) sz = 14;

  __shared__ float v[14][260];
  __shared__ float adjb[14][16];

#pragma unroll
  for (int i = 0; i < 14; ++i) {
    float val = 0.f;
    if (i < sz) {
      int f = fingerprints[a0 + i] & 1023;
      val = embed_fp[(size_t)f * HH + tid];
    }
    v[i][tid] = val;
  }
  if (tid < 224) {
    int i = tid >> 4, jj = tid & 15;
    float a = 0.f;
    if (i < sz && jj < sz)
      a = adj[(size_t)(a0 + i) * NATOMS_N + a0 + jj];
    adjb[i][jj] = a;
  }
  __syncthreads();

  float acc[14];
  for (int rd = 0; rd < 2; ++rd) {
    const float* wp0 = (rd ? w_g1 : w_g0) + tid;
#pragma unroll
    for (int i = 0; i < 14; ++i) acc[i] = 0.f;
    for (int k = 0; k < HH; k += 4) {
      float w0 = wp0[(size_t)k * HH];
      float w1 = wp0[(size_t)(k + 1) * HH];
      float w2 = wp0[(size_t)(k + 2) * HH];
      float w3 = wp0[(size_t)(k + 3) * HH];
#pragma unroll
      for (int i = 0; i < 14; ++i) {
        float4 vv = *(const float4*)&v[i][k];
        acc[i] = fmaf(vv.x, w0, acc[i]);
        acc[i] = fmaf(vv.y, w1, acc[i]);
        acc[i] = fmaf(vv.z, w2, acc[i]);
        acc[i] = fmaf(vv.w, w3, acc[i]);
      }
    }
    float bias = (rd ? b_g1 : b_g0)[tid];
    float hreg[14];
#pragma unroll
    for (int i = 0; i < 14; ++i) hreg[i] = fmaxf(acc[i] + bias, 0.f);
#pragma unroll
    for (int i = 0; i < 14; ++i) {
      float s = hreg[i];
#pragma unroll
      for (int jj = 0; jj < 14; ++jj) s = fmaf(adjb[i][jj], hreg[jj], s);
      acc[i] = s;
    }
    if (rd == 0) {
      __syncthreads();
#pragma unroll
      for (int i = 0; i < 14; ++i) v[i][tid] = acc[i];
      __syncthreads();
    }
  }
  float msum = 0.f;
#pragma unroll
  for (int i = 0; i < 14; ++i) if (i < sz) msum += acc[i];
  mol[(size_t)m * HH + tid] = msum;
}

// ---------------------------------------------------------------------------
// mpnn_emb^T[h][d] = sum_m avg[d][m] * mol[m][h]
// ---------------------------------------------------------------------------
__global__ __launch_bounds__(256) void mpnn_emb_k(
    fp avg, const float* __restrict__ mol, float* __restrict__ embT)
{
  int d = blockIdx.x, tid = threadIdx.x;
  float acc = 0.f;
  for (int m = 0; m < NMOL_N; ++m)
    acc += avg[d * NMOL_N + m] * mol[(size_t)m * HH + tid];
  embT[(size_t)tid * LBL + d] = acc;
}

// ---------------------------------------------------------------------------
// GRU, block-local h, fp16-packed weight stream: 256 blocks = g(2) x 128
// batch-pairs; h lives in LDS across all 32 steps (no grid sync). Per step
// each block streams 393 KB of packed weights (half of round 8's fp32) from
// XCD-L2; h/x/accum stay fp32.
// ---------------------------------------------------------------------------
__global__ __launch_bounds__(256) void gru_local2(
    fp xp, const uint2* __restrict__ wPh, fp bhh_c, fp bhh_p,
    float* __restrict__ hcat, const int* __restrict__ idxv)
{
  int blk = blockIdx.x;
  int g = blk >> 7;
  int pair = blk & 127;
  int b1 = pair * 2, b2 = pair * 2 + 1;
  int tid = threadIdx.x;               // = j
  const uint2* wg = wPh + (size_t)g * 64 * 768 + tid;
  fp bhh = g ? bhh_p : bhh_c;
  const float* xpg = xp + (size_t)g * 8192 * 768;

  __shared__ float h1s[260];
  __shared__ float h2s[260];
  h1s[tid] = 0.f;
  h2s[tid] = 0.f;
  float br = bhh[tid], bz = bhh[tid + 256], bn = bhh[tid + 512];
  int id1 = idxv[b1], id2 = idxv[b2];
  __syncthreads();

  for (int t = 0; t < SS; ++t) {
    float s1r = 0.f, s1z = 0.f, s1n = 0.f;
    float s2r = 0.f, s2z = 0.f, s2n = 0.f;
#pragma unroll 4
    for (int k4 = 0; k4 < 64; ++k4) {
      float4 a1 = *(const float4*)&h1s[k4 * 4];
      float4 a2 = *(const float4*)&h2s[k4 * 4];
      const uint2* base = wg + (size_t)k4 * 768;
      uint2 u0 = base[0];              // gate r, 4 fp16
      uint2 u1 = base[256];            // gate z
      uint2 u2 = base[512];            // gate n
      float r0 = hlo(u0.x), r1 = hhi(u0.x), r2 = hlo(u0.y), r3 = hhi(u0.y);
      float z0 = hlo(u1.x), z1 = hhi(u1.x), z2 = hlo(u1.y), z3 = hhi(u1.y);
      float n0 = hlo(u2.x), n1 = hhi(u2.x), n2 = hlo(u2.y), n3 = hhi(u2.y);
      s1r = fmaf(a1.x, r0, s1r); s1r = fmaf(a1.y, r1, s1r);
      s1r = fmaf(a1.z, r2, s1r); s1r = fmaf(a1.w, r3, s1r);
      s1z = fmaf(a1.x, z0, s1z); s1z = fmaf(a1.y, z1, s1z);
      s1z = fmaf(a1.z, z2, s1z); s1z = fmaf(a1.w, z3, s1z);
      s1n = fmaf(a1.x, n0, s1n); s1n = fmaf(a1.y, n1, s1n);
      s1n = fmaf(a1.z, n2, s1n); s1n = fmaf(a1.w, n3, s1n);
      s2r = fmaf(a2.x, r0, s2r); s2r = fmaf(a2.y, r1, s2r);
      s2r = fmaf(a2.z, r2, s2r); s2r = fmaf(a2.w, r3, s2r);
      s2z = fmaf(a2.x, z0, s2z); s2z = fmaf(a2.y, z1, s2z);
      s2z = fmaf(a2.z, z2, s2z); s2z = fmaf(a2.w, z3, s2z);
      s2n = fmaf(a2.x, n0, s2n); s2n = fmaf(a2.y, n1, s2n);
      s2n = fmaf(a2.z, n2, s2n); s2n = fmaf(a2.w, n3, s2n);
    }
    const float* x1 = xpg + ((size_t)b1 * SS + t) * 768;
    const float* x2 = xpg + ((size_t)b2 * SS + t) * 768;
    float r1g = sigm(x1[tid] + s1r + br);
    float z1g = sigm(x1[tid + 256] + s1z + bz);
    float n1g = tanhf(x1[tid + 512] + r1g * (s1n + bn));
    float h1new = (1.f - z1g) * n1g + z1g * h1s[tid];
    float r2g = sigm(x2[tid] + s2r + br);
    float z2g = sigm(x2[tid + 256] + s2z + bz);
    float n2g = tanhf(x2[tid + 512] + r2g * (s2n + bn));
    float h2new = (1.f - z2g) * n2g + z2g * h2s[tid];
    __syncthreads();                   // all h reads of this step done
    h1s[tid] = h1new;
    h2s[tid] = h2new;
    if (t == id1) hcat[(size_t)b1 * 512 + g * 256 + tid] = fmaxf(h1new, 0.f);
    if (t == id2) hcat[(size_t)b2 * 512 + g * 256 + tid] = fmaxf(h2new, 0.f);
    __syncthreads();
  }
}

// ---------------------------------------------------------------------------
// fp32 GEMM for query: C[M,N] = A[M,K] @ W[K,N] + bias
// ---------------------------------------------------------------------------
__global__ __launch_bounds__(256) void gemm_f32(
    const float* __restrict__ A, fp W, fp bias, float* __restrict__ C,
    int M, int N, int K)
{
  int ntiles = N >> 4;
  int mt = blockIdx.x / ntiles, nt = blockIdx.x - mt * ntiles;
  int m0 = mt << 4, n0 = nt << 4;
  int tid = threadIdx.x;
  int ni = tid & 15, mi = tid >> 4;
  __shared__ float As[16][68];
  float acc = 0.f;
  for (int k0 = 0; k0 < K; k0 += 64) {
    __syncthreads();
    for (int i = tid; i < 1024; i += 256) {
      int r = i >> 6, kk = i & 63;
      As[r][kk] = A[(size_t)(m0 + r) * K + k0 + kk];
    }
    __syncthreads();
    const float* wp = W + (size_t)k0 * N + n0 + ni;
#pragma unroll 4
    for (int kk = 0; kk < 64; ++kk)
      acc = fmaf(As[mi][kk], wp[(size_t)kk * N], acc);
  }
  acc += bias[n0 + ni];
  C[(size_t)(m0 + mi) * N + n0 + ni] = acc;
}

// ---------------------------------------------------------------------------
// fused tail per batch row: match/x2/LN (mpnn_att) + bip/masked-linear + mul
// ---------------------------------------------------------------------------
__global__ __launch_bounds__(256) void tail_fused(
    const float* __restrict__ query, const float* __restrict__ embT,
    fp w_out, fp b_out, fp gamma, fp beta,
    fp w_bip, fp b_bip, const float* __restrict__ mw,
    float* __restrict__ out)
{
  int b = blockIdx.x, tid = threadIdx.x;
  __shared__ float q[HH];
  __shared__ float mrow[LBL];
  __shared__ float bips[NSUBS];
  __shared__ float red[256];
  q[tid] = query[(size_t)b * HH + tid];
  __syncthreads();
  if (tid < LBL) {
    float acc = 0.f;
    for (int k = 0; k < HH; ++k) acc += q[k] * embT[(size_t)k * LBL + tid];
    mrow[tid] = sigm(acc);
  }
  for (int s = tid; s < NSUBS; s += 256) {
    float acc = b_bip[s];
    for (int k = 0; k < HH; ++k) acc += q[k] * w_bip[(size_t)k * NSUBS + s];
    bips[s] = acc;
  }
  __syncthreads();
  float x2 = 0.f;
  if (tid < LBL) {
    float acc = b_out[tid] + mrow[tid];
    for (int jj = 0; jj < LBL; ++jj) acc += mrow[jj] * w_out[jj * LBL + tid];
    x2 = acc;
  }
  red[tid] = (tid < LBL) ? x2 : 0.f;
  __syncthreads();
  for (int s = 128; s > 0; s >>= 1) {
    if (tid < s) red[tid] += red[tid + s];
    __syncthreads();
  }
  float mu = red[0] / (float)LBL;
  __syncthreads();
  float dv = (tid < LBL) ? (x2 - mu) : 0.f;
  red[tid] = dv * dv;
  __syncthreads();
  for (int s = 128; s > 0; s >>= 1) {
    if (tid < s) red[tid] += red[tid + s];
    __syncthreads();
  }
  float var = red[0] / (float)LBL;
  if (tid < LBL) {
    float matt = (x2 - mu) * rsqrtf(var + 1e-5f) * gamma[tid] + beta[tid];
    float acc = 0.f;
    for (int s = 0; s < NSUBS; ++s) acc += bips[s] * mw[(size_t)s * LBL + tid];
    out[(size_t)b * LBL + tid] = acc * matt;
  }
}

// ---------------------------------------------------------------------------
extern "C" void kernel_launch(void* const* d_in, const int* in_sizes, int n_in,
                              void* d_out, int out_size, void* d_ws, size_t ws_size,
                              hipStream_t stream)
{
  fp x_c   = (fp)d_in[0];
  fp x_p   = (fp)d_in[1];
  const int* mask = (const int*)d_in[2];
  fp wih_c = (fp)d_in[3];
  fp whh_c = (fp)d_in[4];
  fp bih_c = (fp)d_in[5];
  fp bhh_c = (fp)d_in[6];
  fp wih_p = (fp)d_in[7];
  fp whh_p = (fp)d_in[8];
  fp bih_p = (fp)d_in[9];
  fp bhh_p = (fp)d_in[10];
  fp w_query = (fp)d_in[11];
  fp b_query = (fp)d_in[12];
  fp w_bip = (fp)d_in[13];
  fp b_bip = (fp)d_in[14];
  fp w_masklin = (fp)d_in[15];
  fp ddi = (fp)d_in[16];
  fp embed_fp = (fp)d_in[17];
  const int* fingerprints = (const int*)d_in[18];
  fp adj = (fp)d_in[19];
  const int* seg = (const int*)d_in[20];
  fp w_g0 = (fp)d_in[21];
  fp b_g0 = (fp)d_in[22];
  fp w_g1 = (fp)d_in[23];
  fp b_g1 = (fp)d_in[24];
  fp avg = (fp)d_in[25];
  fp w_out = (fp)d_in[26];
  fp b_out = (fp)d_in[27];
  fp gamma = (fp)d_in[28];
  fp beta = (fp)d_in[29];
  float* out = (float*)d_out;

  char* w = (char*)d_ws;
  size_t off = 0;
  auto alloc = [&](size_t bytes) -> void* {
    void* p = w + off;
    off = (off + bytes + 255) & ~(size_t)255;
    return p;
  };

  float* xp   = (float*)alloc((size_t)2 * 8192 * 768 * 4);   // 50.3 MB
  uint2* wPh  = (uint2*)alloc((size_t)2 * 64 * 768 * 8);     // 786 KB
  float* mol  = (float*)alloc((size_t)NMOL_N * HH * 4);
  float* embT = (float*)alloc((size_t)HH * LBL * 4);
  float* hcat = (float*)alloc((size_t)BB * 2 * HH * 4);
  float* query = (float*)alloc((size_t)BB * HH * 4);
  float* mw   = (float*)alloc((size_t)NSUBS * LBL * 4);
  int* idxv   = (int*)alloc(256 * 4);
  int* mstart = (int*)alloc((NMOL_N + 1) * 4);

  prep_kernel<<<134, 256, 0, stream>>>(mask, idxv, seg, mstart, w_masklin, ddi,
                                       mw, whh_c, whh_p, wPh);

  xp_gemm<<<dim3(24576, 2), 256, 0, stream>>>(x_c, x_p, wih_c, wih_p,
                                              bih_c, bih_p, xp);

  mpnn_mol<<<NMOL_N, 256, 0, stream>>>(fingerprints, embed_fp, adj, mstart,
                                       w_g0, b_g0, w_g1, b_g1, mol);
  mpnn_emb_k<<<LBL, 256, 0, stream>>>(avg, mol, embT);

  gru_local2<<<256, 256, 0, stream>>>(xp, wPh, bhh_c, bhh_p, hcat, idxv);

  gemm_f32<<<256, 256, 0, stream>>>(hcat, w_query, b_query, query, BB, HH, 2 * HH);
  tail_fused<<<BB, 256, 0, stream>>>(query, embT, w_out, b_out, gamma, beta,
                                     w_bip, b_bip, mw, out);
}